// Round 10
// baseline (140.001 us; speedup 1.0000x reference)
//
#include <hip/hip_runtime.h>
#include <stdint.h>

#define C 64
#define HH 112
#define WWD 112
#define HW 12544
#define NB 32
#define MTOT (NB*HW)
#define PLANE_SH 25088      // shorts per plane stride (plane = 50176 bytes)

typedef int v4i  __attribute__((ext_vector_type(4)));
typedef int v16i __attribute__((ext_vector_type(16)));
typedef unsigned long long ull;

__device__ __forceinline__ uint32_t sgn_byte(float v) {
    return v > 0.f ? 1u : (v < 0.f ? 0xFFu : 0u);
}

// ---- K0: weight prep (1 block): A8[o][tap][c] int8 signs + wscale
__global__ __launch_bounds__(256) void k_wprep(
        const float* __restrict__ w, char* __restrict__ A8,
        float* __restrict__ wscale) {
    int t = threadIdx.x;
    int o = t >> 2, part = t & 3;
    float s = 0.f;
    for (int cc = 0; cc < 16; ++cc) {
        int c = part*16 + cc;
        const float* wp = w + ((size_t)o*C + c)*9;
        #pragma unroll
        for (int tap = 0; tap < 9; ++tap) {
            float v = wp[tap];
            s += fabsf(v);
            A8[(o*9 + tap)*64 + c] = v > 0.f ? (char)1 : (char)-1;
        }
    }
    __shared__ float pabs[256];
    pabs[t] = s;
    __syncthreads();
    if (t < 64)
        wscale[t] = (pabs[t*4]+pabs[t*4+1]+pabs[t*4+2]+pabs[t*4+3]) * (1.0f/576.0f);
}

// ---- K1: fused pack+conv. Block = (row-pair, image). Thread (ri, c) streams
//  112 floats of x (28 contiguous float4 loads), sign-packs, 4x4 byte-transpose
//  within quad (shfl_xor + v_perm), dword-writes NHWC into LDS (72B col stride).
//  Then the i8-MFMA loop (unchanged) produces int16 conv values.
__global__ __launch_bounds__(256) void k_conv(
        const float* __restrict__ x, const float* __restrict__ b0,
        const char* __restrict__ A8, short* __restrict__ cv16) {
    __shared__ ull ldsq[4*114*9];       // 32832 B
    char* ldsb = (char*)ldsq;
    int n  = blockIdx.y;
    int rb = blockIdx.x * 2;            // output rows rb, rb+1

    int wv = threadIdx.x >> 6;          // staged row index ri (wave-uniform)
    int L  = threadIdx.x & 63;          // channel c
    int Rr = rb - 1 + wv;
    float bc = b0[L];

    // zero halo cols 0 and 113 (4 rows x 2 cols x 9 ulongs = 72)
    if (threadIdx.x < 72) {
        int r = threadIdx.x / 18, rest = threadIdx.x % 18;
        int col = (rest / 9) * 113, q = rest % 9;
        ldsq[(size_t)(r*114 + col)*9 + q] = 0ull;
    }

    int k = L & 3, g = L >> 2;
    uint32_t sel1 = (k & 1) ? 0x07030501u : 0x02060004u;
    uint32_t sel2 = (k & 2) ? 0x07060302u : 0x01000504u;

    if (Rr >= 0 && Rr < HH) {
        const float4* src = (const float4*)(x + (size_t)n*C*HW + (size_t)L*HW
                                              + (size_t)Rr*WWD);
        #pragma unroll
        for (int j = 0; j < 28; ++j) {
            float4 v = src[j];
            uint32_t d = sgn_byte(v.x + bc)        | (sgn_byte(v.y + bc) << 8)
                       | (sgn_byte(v.z + bc) << 16) | (sgn_byte(v.w + bc) << 24);
            // 4x4 byte transpose across the quad: lane k ends with col 4j+k,
            // byte i = channel 4g+i  (verified lane-by-lane)
            uint32_t e  = (uint32_t)__shfl_xor((int)d, 1);
            uint32_t r1 = __builtin_amdgcn_perm(d, e, sel1);
            uint32_t f  = (uint32_t)__shfl_xor((int)r1, 2);
            uint32_t r2 = __builtin_amdgcn_perm(r1, f, sel2);
            int col = 4*j + k;
            *(uint32_t*)&ldsb[(size_t)(wv*114 + col + 1)*72 + g*4] = r2;
        }
    } else {
        #pragma unroll
        for (int j = 0; j < 28; ++j) {
            int col = 4*j + k;
            *(uint32_t*)&ldsb[(size_t)(wv*114 + col + 1)*72 + g*4] = 0u;
        }
    }

    int lane  = threadIdx.x & 63;
    int wvi   = threadIdx.x >> 6;
    int ot    = wvi & 1;                // o-half
    int gsel  = lane >> 5;              // k-group
    int olane = ot*32 + (lane & 31);

    v4i afr[9][2];
    #pragma unroll
    for (int tap = 0; tap < 9; ++tap) {
        #pragma unroll
        for (int h = 0; h < 2; ++h)
            afr[tap][h] = *(const v4i*)(A8 + (size_t)(olane*9 + tap)*64 + h*32 + gsel*16);
    }
    __syncthreads();

    for (int T = (wvi >> 1); T < 7; T += 2) {
        int px   = T*32 + (lane & 31);          // 0..223 within row-pair
        int roff = px >= WWD ? 1 : 0;
        int cpx  = px - roff*WWD;
        v16i accA = {0,0,0,0,0,0,0,0,0,0,0,0,0,0,0,0};
        v16i accB = {0,0,0,0,0,0,0,0,0,0,0,0,0,0,0,0};
        #pragma unroll
        for (int kh = 0; kh < 3; ++kh) {
            #pragma unroll
            for (int kw = 0; kw < 3; ++kw) {
                const ull* bp = &ldsq[((size_t)((roff+kh)*114 + (cpx+kw)))*9];
                ull lo0 = bp[gsel*2],     hi0 = bp[gsel*2 + 1];
                ull lo1 = bp[gsel*2 + 4], hi1 = bp[gsel*2 + 5];
                v4i b0v = {(int)lo0, (int)(lo0>>32), (int)hi0, (int)(hi0>>32)};
                v4i b1v = {(int)lo1, (int)(lo1>>32), (int)hi1, (int)(hi1>>32)};
                accA = __builtin_amdgcn_mfma_i32_32x32x32_i8(afr[kh*3+kw][0], b0v, accA, 0, 0, 0);
                accB = __builtin_amdgcn_mfma_i32_32x32x32_i8(afr[kh*3+kw][1], b1v, accB, 0, 0, 0);
            }
        }
        v16i acc = accA + accB;
        size_t pixbase = (size_t)rb*WWD + px;
        #pragma unroll
        for (int r = 0; r < 16; ++r) {
            int o = ot*32 + (r & 3) + 8*(r >> 2) + 4*gsel;
            cv16[(size_t)(n*C + o)*PLANE_SH + pixbase] = (short)acc[r];
        }
    }
}

// ---- K2: per-plane exact integer stats (no atomics, no zeroing)
__global__ __launch_bounds__(256) void k_stats(
        const short* __restrict__ cv16, int* __restrict__ ps,
        long long* __restrict__ pq) {
    int plane = blockIdx.x;
    const uint2* p = (const uint2*)(cv16 + (size_t)plane*PLANE_SH);
    int s = 0; unsigned q = 0;
    for (int i = threadIdx.x; i < 3136; i += 256) {
        uint2 u = p[i];
        int v0 = (int)(short)(u.x & 0xFFFF), v1 = (int)(short)(u.x >> 16);
        int v2 = (int)(short)(u.y & 0xFFFF), v3 = (int)(short)(u.y >> 16);
        s += (v0+v1) + (v2+v3);
        q += (unsigned)(v0*v0 + v1*v1) + (unsigned)(v2*v2 + v3*v3);
    }
    __shared__ int ls[256];
    __shared__ unsigned long long lq[256];
    ls[threadIdx.x] = s; lq[threadIdx.x] = q;
    __syncthreads();
    for (int st = 128; st > 0; st >>= 1) {
        if ((int)threadIdx.x < st) {
            ls[threadIdx.x] += ls[threadIdx.x+st];
            lq[threadIdx.x] += lq[threadIdx.x+st];
        }
        __syncthreads();
    }
    if (threadIdx.x == 0) { ps[plane] = ls[0]; pq[plane] = (long long)lq[0]; }
}

// ---- K3: streaming finish (register-staged in-place), one block per plane
__global__ __launch_bounds__(256) void k_finish(
        const short* __restrict__ cv16, const float* __restrict__ x,
        const int* __restrict__ ps, const long long* __restrict__ pq,
        const float* __restrict__ wscale, const float* __restrict__ gamma,
        const float* __restrict__ beta, const float* __restrict__ b1,
        const float* __restrict__ alpha, const float* __restrict__ b2,
        float* __restrict__ out) {
    int o = blockIdx.x, n = blockIdx.y;
    size_t plane = (size_t)n*C + o;

    int s = 0; long long q = 0;
    #pragma unroll 8
    for (int nn = 0; nn < NB; ++nn) { s += ps[nn*C + o]; q += pq[nn*C + o]; }
    const float inv = 1.0f / (float)MTOT;
    float sc   = wscale[o];
    float mean = (float)s * inv;
    float ek2  = (float)q * inv;
    float mu   = sc * mean;
    float var  = sc*sc*ek2 - mu*mu;
    float g    = gamma[o] * rsqrtf(var + 1e-5f);
    float A    = g * sc;
    float B    = beta[o] - g*mu + b1[o];
    float al   = alpha[o];
    float bb2  = b2[o];

    const uint2* cv2 = (const uint2*)(cv16 + plane*PLANE_SH);
    uint2 rbuf[13];
    #pragma unroll
    for (int k = 0; k < 13; ++k) {
        int i = threadIdx.x + k*256;
        if (i < 3136) rbuf[k] = cv2[i];
    }
    __syncthreads();

    const float4* x4 = (const float4*)x + plane*3136;
    float4*       o4 = (float4*)out     + plane*3136;
    #pragma unroll
    for (int k = 0; k < 13; ++k) {
        int i = threadIdx.x + k*256;
        if (i < 3136) {
            uint2 u = rbuf[k];
            float4 xv = x4[i], r;
            float t;
            t = A * (float)(int)(short)(u.x & 0xFFFF) + B + xv.x; t = t > 0.f ? t : al*t; r.x = t + bb2;
            t = A * (float)(int)(short)(u.x >> 16)    + B + xv.y; t = t > 0.f ? t : al*t; r.y = t + bb2;
            t = A * (float)(int)(short)(u.y & 0xFFFF) + B + xv.z; t = t > 0.f ? t : al*t; r.z = t + bb2;
            t = A * (float)(int)(short)(u.y >> 16)    + B + xv.w; t = t > 0.f ? t : al*t; r.w = t + bb2;
            o4[i] = r;
        }
    }
}

extern "C" void kernel_launch(void* const* d_in, const int* in_sizes, int n_in,
                              void* d_out, int out_size, void* d_ws, size_t ws_size,
                              hipStream_t stream) {
    const float* x     = (const float*)d_in[0];
    const float* b0    = (const float*)d_in[1];
    const float* w     = (const float*)d_in[2];
    const float* gamma = (const float*)d_in[3];
    const float* beta  = (const float*)d_in[4];
    const float* b1    = (const float*)d_in[5];
    const float* alpha = (const float*)d_in[6];
    const float* b2    = (const float*)d_in[7];

    char* ws = (char*)d_ws;
    char*      A8     = ws;                                   // 36,864 B
    float*     wscale = (float*)(ws + 36864);                 // 256 B
    int*       ps     = (int*)(ws + 37120);                   // 8,192 B
    long long* pq     = (long long*)(ws + 45312);             // 16,384 B

    short* cv16 = (short*)d_out;

    hipLaunchKernelGGL(k_wprep, dim3(1), dim3(256), 0, stream, w, A8, wscale);
    hipLaunchKernelGGL(k_conv, dim3(56, 32), dim3(256), 0, stream,
                       x, b0, A8, cv16);
    hipLaunchKernelGGL(k_stats, dim3(2048), dim3(256), 0, stream,
                       cv16, ps, pq);
    hipLaunchKernelGGL(k_finish, dim3(64, 32), dim3(256), 0, stream,
                       cv16, x, ps, pq, wscale, gamma, beta, b1, alpha, b2,
                       (float*)d_out);
}

// Round 11
// 129.717 us; speedup vs baseline: 1.0793x; 1.0793x over previous
//
#include <hip/hip_runtime.h>
#include <stdint.h>

#define C 64
#define HH 112
#define WWD 112
#define HW 12544
#define NB 32
#define MTOT (NB*HW)
#define PLANE_SH 25088      // shorts per plane stride

typedef int v4i  __attribute__((ext_vector_type(4)));
typedef int v16i __attribute__((ext_vector_type(16)));
typedef unsigned long long ull;

__device__ __forceinline__ uint32_t sgn_byte(float v) {
    return v > 0.f ? 1u : (v < 0.f ? 0xFFu : 0u);
}

// ---- K0: weight prep (1 block): A8[o][tap][c] int8 signs + wscale
__global__ __launch_bounds__(256) void k_wprep(
        const float* __restrict__ w, char* __restrict__ A8,
        float* __restrict__ wscale) {
    int t = threadIdx.x;
    int o = t >> 2, part = t & 3;
    float s = 0.f;
    for (int cc = 0; cc < 16; ++cc) {
        int c = part*16 + cc;
        const float* wp = w + ((size_t)o*C + c)*9;
        #pragma unroll
        for (int tap = 0; tap < 9; ++tap) {
            float v = wp[tap];
            s += fabsf(v);
            A8[(o*9 + tap)*64 + c] = v > 0.f ? (char)1 : (char)-1;
        }
    }
    __shared__ float pabs[256];
    pabs[t] = s;
    __syncthreads();
    if (t < 64)
        wscale[t] = (pabs[t*4]+pabs[t*4+1]+pabs[t*4+2]+pabs[t*4+3]) * (1.0f/576.0f);
}

// ---- K1: fused pack+conv. Staging now lane=pixel (R6-proven pattern):
//  thread=(staged row, col) loops 64 channels of lane-consecutive dword loads,
//  packs the pixel's NHWC 64 bytes in-register, 4x b128 LDS writes.
//  MFMA loop unchanged (bit-identical cv16).
__global__ __launch_bounds__(256) void k_conv(
        const float* __restrict__ x, const float* __restrict__ b0,
        const char* __restrict__ A8, short* __restrict__ cv16) {
    __shared__ ull ldsq[4*114*9];       // 32832 B, 72B col stride
    char* ldsb = (char*)ldsq;
    int n  = blockIdx.y;
    int rb = blockIdx.x * 2;            // output rows rb, rb+1

    // zero halo cols 0 and 113 (4 rows x 2 cols x 9 ulongs = 72)
    if (threadIdx.x < 72) {
        int r = threadIdx.x / 18, rest = threadIdx.x % 18;
        int col = (rest / 9) * 113, q = rest % 9;
        ldsq[(size_t)(r*114 + col)*9 + q] = 0ull;
    }

    // staging: 448 items = 224 threads x 2 iterations
    int t = threadIdx.x;
    #pragma unroll
    for (int it = 0; it < 2; ++it) {
        if (t < 224) {
            int second = t >= 112;
            int ri  = it*2 + second;
            int col = t - second*112;
            int Rr  = rb - 1 + ri;
            uint32_t d[16];
            if (Rr >= 0 && Rr < HH) {
                const float* src = x + (size_t)n*C*HW + (size_t)Rr*WWD + col;
                #pragma unroll
                for (int cq = 0; cq < 16; ++cq) {
                    uint32_t acc = 0;
                    #pragma unroll
                    for (int j = 0; j < 4; ++j) {
                        int c = cq*4 + j;
                        float v = src[(size_t)c*HW] + b0[c];
                        acc |= sgn_byte(v) << (8*j);
                    }
                    d[cq] = acc;
                }
            } else {
                #pragma unroll
                for (int cq = 0; cq < 16; ++cq) d[cq] = 0u;
            }
            uint4* dst = (uint4*)&ldsb[(size_t)(ri*114 + col + 1)*72];
            dst[0] = make_uint4(d[0], d[1], d[2], d[3]);
            dst[1] = make_uint4(d[4], d[5], d[6], d[7]);
            dst[2] = make_uint4(d[8], d[9], d[10], d[11]);
            dst[3] = make_uint4(d[12], d[13], d[14], d[15]);
        }
    }

    int lane  = threadIdx.x & 63;
    int wvi   = threadIdx.x >> 6;
    int ot    = wvi & 1;                // o-half
    int gsel  = lane >> 5;              // k-group
    int olane = ot*32 + (lane & 31);

    v4i afr[9][2];
    #pragma unroll
    for (int tap = 0; tap < 9; ++tap) {
        #pragma unroll
        for (int h = 0; h < 2; ++h)
            afr[tap][h] = *(const v4i*)(A8 + (size_t)(olane*9 + tap)*64 + h*32 + gsel*16);
    }
    __syncthreads();

    for (int T = (wvi >> 1); T < 7; T += 2) {
        int px   = T*32 + (lane & 31);          // 0..223 within row-pair
        int roff = px >= WWD ? 1 : 0;
        int cpx  = px - roff*WWD;
        v16i accA = {0,0,0,0,0,0,0,0,0,0,0,0,0,0,0,0};
        v16i accB = {0,0,0,0,0,0,0,0,0,0,0,0,0,0,0,0};
        #pragma unroll
        for (int kh = 0; kh < 3; ++kh) {
            #pragma unroll
            for (int kw = 0; kw < 3; ++kw) {
                const ull* bp = &ldsq[((size_t)((roff+kh)*114 + (cpx+kw)))*9];
                ull lo0 = bp[gsel*2],     hi0 = bp[gsel*2 + 1];
                ull lo1 = bp[gsel*2 + 4], hi1 = bp[gsel*2 + 5];
                v4i b0v = {(int)lo0, (int)(lo0>>32), (int)hi0, (int)(hi0>>32)};
                v4i b1v = {(int)lo1, (int)(lo1>>32), (int)hi1, (int)(hi1>>32)};
                accA = __builtin_amdgcn_mfma_i32_32x32x32_i8(afr[kh*3+kw][0], b0v, accA, 0, 0, 0);
                accB = __builtin_amdgcn_mfma_i32_32x32x32_i8(afr[kh*3+kw][1], b1v, accB, 0, 0, 0);
            }
        }
        v16i acc = accA + accB;
        size_t pixbase = (size_t)rb*WWD + px;
        #pragma unroll
        for (int r = 0; r < 16; ++r) {
            int o = ot*32 + (r & 3) + 8*(r >> 2) + 4*gsel;
            cv16[(size_t)(n*C + o)*PLANE_SH + pixbase] = (short)acc[r];
        }
    }
}

// ---- K2: per-plane exact integer stats (no atomics, no zeroing)
__global__ __launch_bounds__(256) void k_stats(
        const short* __restrict__ cv16, int* __restrict__ ps,
        long long* __restrict__ pq) {
    int plane = blockIdx.x;
    const uint2* p = (const uint2*)(cv16 + (size_t)plane*PLANE_SH);
    int s = 0; unsigned q = 0;
    for (int i = threadIdx.x; i < 3136; i += 256) {
        uint2 u = p[i];
        int v0 = (int)(short)(u.x & 0xFFFF), v1 = (int)(short)(u.x >> 16);
        int v2 = (int)(short)(u.y & 0xFFFF), v3 = (int)(short)(u.y >> 16);
        s += (v0+v1) + (v2+v3);
        q += (unsigned)(v0*v0 + v1*v1) + (unsigned)(v2*v2 + v3*v3);
    }
    __shared__ int ls[256];
    __shared__ unsigned long long lq[256];
    ls[threadIdx.x] = s; lq[threadIdx.x] = q;
    __syncthreads();
    for (int st = 128; st > 0; st >>= 1) {
        if ((int)threadIdx.x < st) {
            ls[threadIdx.x] += ls[threadIdx.x+st];
            lq[threadIdx.x] += lq[threadIdx.x+st];
        }
        __syncthreads();
    }
    if (threadIdx.x == 0) { ps[plane] = ls[0]; pq[plane] = (long long)lq[0]; }
}

// ---- K3: streaming finish (register-staged in-place), one block per plane
__global__ __launch_bounds__(256) void k_finish(
        const short* __restrict__ cv16, const float* __restrict__ x,
        const int* __restrict__ ps, const long long* __restrict__ pq,
        const float* __restrict__ wscale, const float* __restrict__ gamma,
        const float* __restrict__ beta, const float* __restrict__ b1,
        const float* __restrict__ alpha, const float* __restrict__ b2,
        float* __restrict__ out) {
    int o = blockIdx.x, n = blockIdx.y;
    size_t plane = (size_t)n*C + o;

    int s = 0; long long q = 0;
    #pragma unroll 8
    for (int nn = 0; nn < NB; ++nn) { s += ps[nn*C + o]; q += pq[nn*C + o]; }
    const float inv = 1.0f / (float)MTOT;
    float sc   = wscale[o];
    float mean = (float)s * inv;
    float ek2  = (float)q * inv;
    float mu   = sc * mean;
    float var  = sc*sc*ek2 - mu*mu;
    float g    = gamma[o] * rsqrtf(var + 1e-5f);
    float A    = g * sc;
    float B    = beta[o] - g*mu + b1[o];
    float al   = alpha[o];
    float bb2  = b2[o];

    const uint2* cv2 = (const uint2*)(cv16 + plane*PLANE_SH);
    uint2 rbuf[13];
    #pragma unroll
    for (int k = 0; k < 13; ++k) {
        int i = threadIdx.x + k*256;
        if (i < 3136) rbuf[k] = cv2[i];
    }
    __syncthreads();

    const float4* x4 = (const float4*)x + plane*3136;
    float4*       o4 = (float4*)out     + plane*3136;
    #pragma unroll
    for (int k = 0; k < 13; ++k) {
        int i = threadIdx.x + k*256;
        if (i < 3136) {
            uint2 u = rbuf[k];
            float4 xv = x4[i], r;
            float t;
            t = A * (float)(int)(short)(u.x & 0xFFFF) + B + xv.x; t = t > 0.f ? t : al*t; r.x = t + bb2;
            t = A * (float)(int)(short)(u.x >> 16)    + B + xv.y; t = t > 0.f ? t : al*t; r.y = t + bb2;
            t = A * (float)(int)(short)(u.y & 0xFFFF) + B + xv.z; t = t > 0.f ? t : al*t; r.z = t + bb2;
            t = A * (float)(int)(short)(u.y >> 16)    + B + xv.w; t = t > 0.f ? t : al*t; r.w = t + bb2;
            o4[i] = r;
        }
    }
}

extern "C" void kernel_launch(void* const* d_in, const int* in_sizes, int n_in,
                              void* d_out, int out_size, void* d_ws, size_t ws_size,
                              hipStream_t stream) {
    const float* x     = (const float*)d_in[0];
    const float* b0    = (const float*)d_in[1];
    const float* w     = (const float*)d_in[2];
    const float* gamma = (const float*)d_in[3];
    const float* beta  = (const float*)d_in[4];
    const float* b1    = (const float*)d_in[5];
    const float* alpha = (const float*)d_in[6];
    const float* b2    = (const float*)d_in[7];

    char* ws = (char*)d_ws;
    char*      A8     = ws;                                   // 36,864 B
    float*     wscale = (float*)(ws + 36864);                 // 256 B
    int*       ps     = (int*)(ws + 37120);                   // 8,192 B
    long long* pq     = (long long*)(ws + 45312);             // 16,384 B

    short* cv16 = (short*)d_out;

    hipLaunchKernelGGL(k_wprep, dim3(1), dim3(256), 0, stream, w, A8, wscale);
    hipLaunchKernelGGL(k_conv, dim3(56, 32), dim3(256), 0, stream,
                       x, b0, A8, cv16);
    hipLaunchKernelGGL(k_stats, dim3(2048), dim3(256), 0, stream,
                       cv16, ps, pq);
    hipLaunchKernelGGL(k_finish, dim3(64, 32), dim3(256), 0, stream,
                       cv16, x, ps, pq, wscale, gamma, beta, b1, alpha, b2,
                       (float*)d_out);
}